// Round 2
// baseline (937.535 us; speedup 1.0000x reference)
//
#include <hip/hip_runtime.h>

constexpr int T = 168;
constexpr int P = 16;
constexpr int H = 24;

typedef float v2f __attribute__((ext_vector_type(2)));

__device__ __forceinline__ v2f mk2(float a, float b) { v2f r; r[0] = a; r[1] = b; return r; }
__device__ __forceinline__ v2f bc2(float a)          { v2f r; r[0] = a; r[1] = a; return r; }
// 2 fp32 FMAs in one instruction (v_pk_fma_f32) — the only path to the
// 157 TF fp32 rate; plain v_fma_f32 caps at ~half (m07).
__device__ __forceinline__ v2f pkfma(v2f a, v2f b, v2f c) {
    return __builtin_elementwise_fma(a, b, c);
}

__device__ __forceinline__ float rcp_f(float x) { return __builtin_amdgcn_rcpf(x); }
__device__ __forceinline__ float sigm_f(float x) { return rcp_f(1.f + __expf(-x)); }
// tanh(x) = 2*sigmoid(2x) - 1
__device__ __forceinline__ float tanh_fast(float x) {
    return fmaf(2.f, rcp_f(1.f + __expf(-2.f * x)), -1.f);
}

#define KEEP2(v) asm volatile("" : "+v"(v))
// Intra-wave LDS write->read ordering + compiler reorder fence.
#define LDS_SYNC() asm volatile("s_waitcnt lgkmcnt(0)" ::: "memory")

// 4 packed FMAs: acc += v4.{x,y,z,w} * w[b..b+3]
#define PK4(acc_, v4_, w_, b_) do {                       \
    acc_ = pkfma(bc2((v4_).x), (w_)[(b_)],     acc_);     \
    acc_ = pkfma(bc2((v4_).y), (w_)[(b_) + 1], acc_);     \
    acc_ = pkfma(bc2((v4_).z), (w_)[(b_) + 2], acc_);     \
    acc_ = pkfma(bc2((v4_).w), (w_)[(b_) + 3], acc_); } while (0)

// Gate nonlinearity + state update + h store. tdst==nullptr folds away after
// inlining (layer-2 needs no tanh(h) during the loop).
__device__ __forceinline__ void act_store(v2f g, int lane, int half,
                                          float& c, float* hdst, float* tdst)
{
    float a0 = sigm_f(g[0]);                        // i (half0) | f (half1)
    float px = (half == 0) ? g[1] + g[1] : g[1];
    float sv = sigm_f(px);
    float a1 = (half == 0) ? sv + sv - 1.f : sv;    // tanh(g) | o
    float fa = __shfl(a0, lane + 24);
    float oa = __shfl(a1, lane + 24);
    c = fmaf(fa, c, a0 * a1);
    float hv = oa * tanh_fast(c);
    if (tdst) {
        float th = tanh_fast(hv);
        if (lane < H) { hdst[lane] = hv; tdst[lane] = th; }
    } else {
        if (lane < H) hdst[lane] = hv;
    }
}

// R8: software-pipeline the two LSTM layers by one timestep.
// L2[t] (reads t1[t], h2[t-1]) and L1[t+1] (reads x[t+1], h1[t]) are
// independent -> compute them interleaved in one phase with ONE lgkmcnt(0)
// drain per step instead of two. Gate accumulators split (x/t-part + h-part)
// so no dependent FMA chain exceeds 24 pkfma; 8 independent chains total.
// R9 tweak: x reads as float4 (64B/step/row is 16B-aligned) — removes up to
// 28 VMEM issues/iter if the compiler wasn't already scalarizing them.
// Keeps R4's proven lane layout: lane u in [0,24): gates {i,g} of unit u;
// lane 24+u: gates {f,o}; 2 rows/wave, 2 waves/SIMD, zero barriers.
__global__ __attribute__((amdgpu_flat_work_group_size(64, 64),
                          amdgpu_waves_per_eu(2, 2)))
void lstm2_pipe(const float* __restrict__ x,
                const float* __restrict__ Wih1, const float* __restrict__ Whh1,
                const float* __restrict__ bih1, const float* __restrict__ bhh1,
                const float* __restrict__ Wih2, const float* __restrict__ Whh2,
                const float* __restrict__ bih2, const float* __restrict__ bhh2,
                const float* __restrict__ W1, const float* __restrict__ b1,
                const float* __restrict__ W2, const float* __restrict__ b2,
                float* __restrict__ out)
{
    const int lane = threadIdx.x;                 // 0..63
    const int s    = (lane < 48) ? lane : 47;     // clamp idle lanes
    const int u    = s % H;                       // unit 0..23
    const int half = s / H;                       // 0: {i,g}, 1: {f,o}
    const int q0   = half * H + u;                // i or f gate row
    const int q1   = (2 + half) * H + u;          // g or o gate row
    const int rowA = blockIdx.x * 2;
    const int rowB = rowA + 1;

    // ---- weights as packed pairs: 88 v2f = 176 floats ----
    v2f wx[P];   // Wih1 {q0,q1}
    v2f wh[H];   // Whh1 {q0,q1}
    v2f vx[H];   // Wih2 {q0,q1}
    v2f vh[H];   // Whh2 {q0,q1}
    #pragma unroll
    for (int k = 0; k < P; ++k) wx[k] = mk2(Wih1[q0 * P + k], Wih1[q1 * P + k]);
    #pragma unroll
    for (int k = 0; k < H; ++k) wh[k] = mk2(Whh1[q0 * H + k], Whh1[q1 * H + k]);
    #pragma unroll
    for (int k = 0; k < H; ++k) vx[k] = mk2(Wih2[q0 * H + k], Wih2[q1 * H + k]);
    #pragma unroll
    for (int k = 0; k < H; ++k) vh[k] = mk2(Whh2[q0 * H + k], Whh2[q1 * H + k]);
    v2f bias1 = mk2(bih1[q0] + bhh1[q0], bih1[q1] + bhh1[q1]);
    v2f bias2 = mk2(bih2[q0] + bhh2[q0], bih2[q1] + bhh2[q1]);

    #pragma unroll
    for (int k = 0; k < P; ++k) KEEP2(wx[k]);
    #pragma unroll
    for (int k = 0; k < H; ++k) { KEEP2(wh[k]); KEEP2(vx[k]); KEEP2(vh[k]); }
    KEEP2(bias1); KEEP2(bias2);

    __shared__ __align__(16) float h1s[2][32];        // layer-1 h, per row
    __shared__ __align__(16) float t1s[2][2][32];     // [buf][row] tanh(h1)
    __shared__ __align__(16) float h2s[2][32];        // layer-2 h

    if (lane < H) {
        h1s[0][lane] = 0.f; h1s[1][lane] = 0.f;
        h2s[0][lane] = 0.f; h2s[1][lane] = 0.f;
        t1s[0][0][lane] = 0.f; t1s[0][1][lane] = 0.f;
        t1s[1][0][lane] = 0.f; t1s[1][1][lane] = 0.f;
    }
    LDS_SYNC();

    const float* __restrict__ xA = x + (size_t)rowA * T * P;  // wave-uniform
    const float* __restrict__ xB = x + (size_t)rowB * T * P;  // wave-uniform

    float c1A = 0.f, c1B = 0.f, c2A = 0.f, c2B = 0.f;

    // ---- prologue: L1 step 0 (h1 = 0 -> x-part + bias only) ----
    {
        v2f gA = bias1, gB = bias1;
        #pragma unroll
        for (int j = 0; j < P / 4; ++j) {
            float4 va = ((const float4*)xA)[j];
            float4 vb = ((const float4*)xB)[j];
            PK4(gA, va, wx, 4 * j);
            PK4(gB, vb, wx, 4 * j);
        }
        act_store(gA, lane, half, c1A, h1s[0], t1s[0][0]);
        act_store(gB, lane, half, c1B, h1s[1], t1s[0][1]);
    }
    LDS_SYNC();

    int tb = 0;
    for (int t = 0; t < T - 1; ++t) {
        // ===== L1 gates for step t+1: x-part (independent, issues loads early)
        const float4* xa4 = (const float4*)(xA + (t + 1) * P);
        const float4* xb4 = (const float4*)(xB + (t + 1) * P);
        v2f gxA = bias1, gxB = bias1;
        #pragma unroll
        for (int j = 0; j < P / 4; ++j) {
            float4 va = xa4[j];
            float4 vb = xb4[j];
            PK4(gxA, va, wx, 4 * j);
            PK4(gxB, vb, wx, 4 * j);
        }

        // ===== interleaved: L1[t+1] h-part || L2[t] t-part || L2[t] h-part
        v2f ghA = bc2(0.f), ghB = bc2(0.f);   // L1 recurrent part
        v2f ftA = bias2,    ftB = bias2;      // L2 input part
        v2f fhA = bc2(0.f), fhB = bc2(0.f);   // L2 recurrent part
        const float* t1a = t1s[tb][0];
        const float* t1b = t1s[tb][1];
        #pragma unroll
        for (int k = 0; k < H / 4; ++k) {
            float4 h1a = ((const float4*)h1s[0])[k];
            float4 h1b = ((const float4*)h1s[1])[k];
            float4 ta4 = ((const float4*)t1a)[k];
            float4 tb4 = ((const float4*)t1b)[k];
            float4 h2a = ((const float4*)h2s[0])[k];
            float4 h2b = ((const float4*)h2s[1])[k];
            PK4(ghA, h1a, wh, 4 * k);  PK4(ghB, h1b, wh, 4 * k);
            PK4(ftA, ta4, vx, 4 * k);  PK4(ftB, tb4, vx, 4 * k);
            PK4(fhA, h2a, vh, 4 * k);  PK4(fhB, h2b, vh, 4 * k);
        }
        v2f gA = gxA + ghA, gB = gxB + ghB;
        v2f fA = ftA + fhA, fB = ftB + fhB;

        // ===== activations: 4 independent chains, then ONE drain =====
        float* td0 = t1s[tb ^ 1][0];
        float* td1 = t1s[tb ^ 1][1];
        act_store(gA, lane, half, c1A, h1s[0], td0);
        act_store(gB, lane, half, c1B, h1s[1], td1);
        act_store(fA, lane, half, c2A, h2s[0], nullptr);
        act_store(fB, lane, half, c2B, h2s[1], nullptr);
        LDS_SYNC();
        tb ^= 1;
    }

    // ---- epilogue: L2 step T-1 ----
    {
        v2f ftA = bias2, ftB = bias2;
        v2f fhA = bc2(0.f), fhB = bc2(0.f);
        const float* t1a = t1s[tb][0];
        const float* t1b = t1s[tb][1];
        #pragma unroll
        for (int k = 0; k < H / 4; ++k) {
            float4 ta4 = ((const float4*)t1a)[k];
            float4 tb4 = ((const float4*)t1b)[k];
            float4 h2a = ((const float4*)h2s[0])[k];
            float4 h2b = ((const float4*)h2s[1])[k];
            PK4(ftA, ta4, vx, 4 * k);  PK4(ftB, tb4, vx, 4 * k);
            PK4(fhA, h2a, vh, 4 * k);  PK4(fhB, h2b, vh, 4 * k);
        }
        v2f fA = ftA + fhA, fB = ftB + fhB;
        act_store(fA, lane, half, c2A, h2s[0], nullptr);
        act_store(fB, lane, half, c2B, h2s[1], nullptr);
    }
    LDS_SYNC();

    // ---- head: tanh -> fc1(16, relu) -> fc2(24), both rows ----
    if (lane < H) {
        t1s[0][0][lane] = tanh_fast(h2s[0][lane]);
        t1s[0][1][lane] = tanh_fast(h2s[1][lane]);
    }
    LDS_SYNC();
    if (lane < 16) {
        float accA = b1[lane], accB = b1[lane];
        #pragma unroll
        for (int j = 0; j < H; ++j) {
            float w = W1[lane * H + j];
            accA = fmaf(t1s[0][0][j], w, accA);
            accB = fmaf(t1s[0][1][j], w, accB);
        }
        h1s[0][lane] = fmaxf(accA, 0.f);
        h1s[1][lane] = fmaxf(accB, 0.f);
    }
    LDS_SYNC();
    if (lane < H) {
        float accA = b2[lane], accB = b2[lane];
        #pragma unroll
        for (int j = 0; j < 16; ++j) {
            float w = W2[lane * 16 + j];
            accA = fmaf(h1s[0][j], w, accA);
            accB = fmaf(h1s[1][j], w, accB);
        }
        out[(size_t)rowA * H + lane] = accA;
        out[(size_t)rowB * H + lane] = accB;
    }
}

extern "C" void kernel_launch(void* const* d_in, const int* in_sizes, int n_in,
                              void* d_out, int out_size, void* d_ws, size_t ws_size,
                              hipStream_t stream)
{
    const float* x    = (const float*)d_in[0];
    const float* Wih1 = (const float*)d_in[1];
    const float* Whh1 = (const float*)d_in[2];
    const float* bih1 = (const float*)d_in[3];
    const float* bhh1 = (const float*)d_in[4];
    const float* Wih2 = (const float*)d_in[5];
    const float* Whh2 = (const float*)d_in[6];
    const float* bih2 = (const float*)d_in[7];
    const float* bhh2 = (const float*)d_in[8];
    const float* W1   = (const float*)d_in[9];
    const float* b1   = (const float*)d_in[10];
    const float* W2   = (const float*)d_in[11];
    const float* b2   = (const float*)d_in[12];
    float* out = (float*)d_out;

    const int B = in_sizes[0] / (T * P);             // 4096
    hipLaunchKernelGGL(lstm2_pipe, dim3(B / 2), dim3(64), 0, stream,
                       x, Wih1, Whh1, bih1, bhh1, Wih2, Whh2, bih2, bhh2,
                       W1, b1, W2, b2, out);
}

// Round 3
// 571.034 us; speedup vs baseline: 1.6418x; 1.6418x over previous
//
#include <hip/hip_runtime.h>

constexpr int T = 168;
constexpr int P = 16;
constexpr int H = 24;

typedef float v2f __attribute__((ext_vector_type(2)));

__device__ __forceinline__ v2f mk2(float a, float b) { v2f r; r[0] = a; r[1] = b; return r; }
__device__ __forceinline__ v2f bc2(float a)          { v2f r; r[0] = a; r[1] = a; return r; }
// 2 fp32 FMAs in one instruction (v_pk_fma_f32).
__device__ __forceinline__ v2f pkfma(v2f a, v2f b, v2f c) {
    return __builtin_elementwise_fma(a, b, c);
}

__device__ __forceinline__ float rcp_f(float x) { return __builtin_amdgcn_rcpf(x); }
__device__ __forceinline__ float sigm_f(float x) { return rcp_f(1.f + __expf(-x)); }
// tanh(x) = 2*sigmoid(2x) - 1
__device__ __forceinline__ float tanh_fast(float x) {
    return fmaf(2.f, rcp_f(1.f + __expf(-2.f * x)), -1.f);
}

#define KEEP2(v) asm volatile("" : "+v"(v))
// Intra-wave LDS write->read ordering + compiler reorder fence.
#define LDS_SYNC() asm volatile("s_waitcnt lgkmcnt(0)" ::: "memory")

// 4 packed FMAs: acc += v4.{x,y,z,w} * w[b..b+3]
#define PK4(acc_, v4_, w_, b_) do {                       \
    acc_ = pkfma(bc2((v4_).x), (w_)[(b_)],     acc_);     \
    acc_ = pkfma(bc2((v4_).y), (w_)[(b_) + 1], acc_);     \
    acc_ = pkfma(bc2((v4_).z), (w_)[(b_) + 2], acc_);     \
    acc_ = pkfma(bc2((v4_).w), (w_)[(b_) + 3], acc_); } while (0)

// Gate nonlinearity + state update + h store. tdst==nullptr folds away.
__device__ __forceinline__ void act_store(v2f g, int lane, int half,
                                          float& c, float* hdst, float* tdst)
{
    float a0 = sigm_f(g[0]);                        // i (half0) | f (half1)
    float px = (half == 0) ? g[1] + g[1] : g[1];
    float sv = sigm_f(px);
    float a1 = (half == 0) ? sv + sv - 1.f : sv;    // tanh(g) | o
    float fa = __shfl(a0, lane + 24);
    float oa = __shfl(a1, lane + 24);
    c = fmaf(fa, c, a0 * a1);
    float hv = oa * tanh_fast(c);
    if (tdst) {
        float th = tanh_fast(hv);
        if (lane < H) { hdst[lane] = hv; tdst[lane] = th; }
    } else {
        if (lane < H) hdst[lane] = hv;
    }
}

// R10: keep R8's layer pipeline (L1[t+1] and L2[t] in one phase, ONE
// lgkmcnt(0) drain/step, t1 double buffer) but fix the R9 spill cascade:
// R9's fat interleave (8 v2f accs + 6 live float4 temps + 176 weight regs)
// pushed peak pressure past the (2,2) allocator's limit -> it collapsed to
// 128 VGPRs and spilled ~55 weights to scratch, reloaded EVERY step
// (WRITE_SIZE 29.5MB vs 0.4MB of output = spill stores; 2.3x slowdown).
// Fixes: (a) L1/L2 bodies sequential in source -> only 4 gate accumulators
// and 2 float4 temps live at once (peak ~215 VGPR); (b) waves_per_eu(1,2):
// spill cap 512 (never spill), allocator free to land <=256 and keep
// 2 waves/SIMD. Lane layout unchanged: lane u in [0,24): gates {i,g} of
// unit u; lane 24+u: {f,o}; 2 rows/wave, zero barriers.
__global__ __attribute__((amdgpu_flat_work_group_size(64, 64),
                          amdgpu_waves_per_eu(1, 2)))
void lstm2_pipe2(const float* __restrict__ x,
                 const float* __restrict__ Wih1, const float* __restrict__ Whh1,
                 const float* __restrict__ bih1, const float* __restrict__ bhh1,
                 const float* __restrict__ Wih2, const float* __restrict__ Whh2,
                 const float* __restrict__ bih2, const float* __restrict__ bhh2,
                 const float* __restrict__ W1, const float* __restrict__ b1,
                 const float* __restrict__ W2, const float* __restrict__ b2,
                 float* __restrict__ out)
{
    const int lane = threadIdx.x;                 // 0..63
    const int s    = (lane < 48) ? lane : 47;     // clamp idle lanes
    const int u    = s % H;                       // unit 0..23
    const int half = s / H;                       // 0: {i,g}, 1: {f,o}
    const int q0   = half * H + u;                // i or f gate row
    const int q1   = (2 + half) * H + u;          // g or o gate row
    const int rowA = blockIdx.x * 2;
    const int rowB = rowA + 1;

    // ---- weights as packed pairs: 88 v2f = 176 floats ----
    v2f wx[P];   // Wih1 {q0,q1}
    v2f wh[H];   // Whh1 {q0,q1}
    v2f vx[H];   // Wih2 {q0,q1}
    v2f vh[H];   // Whh2 {q0,q1}
    #pragma unroll
    for (int k = 0; k < P; ++k) wx[k] = mk2(Wih1[q0 * P + k], Wih1[q1 * P + k]);
    #pragma unroll
    for (int k = 0; k < H; ++k) wh[k] = mk2(Whh1[q0 * H + k], Whh1[q1 * H + k]);
    #pragma unroll
    for (int k = 0; k < H; ++k) vx[k] = mk2(Wih2[q0 * H + k], Wih2[q1 * H + k]);
    #pragma unroll
    for (int k = 0; k < H; ++k) vh[k] = mk2(Whh2[q0 * H + k], Whh2[q1 * H + k]);
    v2f bias1 = mk2(bih1[q0] + bhh1[q0], bih1[q1] + bhh1[q1]);
    v2f bias2 = mk2(bih2[q0] + bhh2[q0], bih2[q1] + bhh2[q1]);

    #pragma unroll
    for (int k = 0; k < P; ++k) KEEP2(wx[k]);
    #pragma unroll
    for (int k = 0; k < H; ++k) { KEEP2(wh[k]); KEEP2(vx[k]); KEEP2(vh[k]); }
    KEEP2(bias1); KEEP2(bias2);

    __shared__ __align__(16) float h1s[2][32];        // layer-1 h, per row
    __shared__ __align__(16) float t1s[2][2][32];     // [buf][row] tanh(h1)
    __shared__ __align__(16) float h2s[2][32];        // layer-2 h

    if (lane < H) {
        h1s[0][lane] = 0.f; h1s[1][lane] = 0.f;
        h2s[0][lane] = 0.f; h2s[1][lane] = 0.f;
        t1s[0][0][lane] = 0.f; t1s[0][1][lane] = 0.f;
        t1s[1][0][lane] = 0.f; t1s[1][1][lane] = 0.f;
    }
    LDS_SYNC();

    const float* __restrict__ xA = x + (size_t)rowA * T * P;  // wave-uniform
    const float* __restrict__ xB = x + (size_t)rowB * T * P;  // wave-uniform

    float c1A = 0.f, c1B = 0.f, c2A = 0.f, c2B = 0.f;

    // ---- prologue: L1 step 0 (h1 = 0 -> x-part + bias only) ----
    {
        v2f gA = bias1, gB = bias1;
        #pragma unroll
        for (int j = 0; j < P / 4; ++j) {
            float4 va = ((const float4*)xA)[j];
            float4 vb = ((const float4*)xB)[j];
            PK4(gA, va, wx, 4 * j);
            PK4(gB, vb, wx, 4 * j);
        }
        act_store(gA, lane, half, c1A, h1s[0], t1s[0][0]);
        act_store(gB, lane, half, c1B, h1s[1], t1s[0][1]);
    }
    LDS_SYNC();

    int tb = 0;
    for (int t = 0; t < T - 1; ++t) {
        // ===== L1 gates for step t+1 (reads x[t+1], h1[t]) =====
        v2f gA = bias1, gB = bias1;
        {
            const float4* xa4 = (const float4*)(xA + (t + 1) * P);
            const float4* xb4 = (const float4*)(xB + (t + 1) * P);
            #pragma unroll
            for (int j = 0; j < P / 4; ++j) {
                float4 va = xa4[j];
                float4 vb = xb4[j];
                PK4(gA, va, wx, 4 * j);
                PK4(gB, vb, wx, 4 * j);
            }
            #pragma unroll
            for (int k = 0; k < H / 4; ++k) {
                float4 ha = ((const float4*)h1s[0])[k];
                float4 hb = ((const float4*)h1s[1])[k];
                PK4(gA, ha, wh, 4 * k);
                PK4(gB, hb, wh, 4 * k);
            }
        }

        // ===== L2 gates for step t (reads t1[t] from buf tb, h2[t-1]) =====
        v2f fA = bias2, fB = bias2;
        {
            const float* t1a = t1s[tb][0];
            const float* t1b = t1s[tb][1];
            #pragma unroll
            for (int k = 0; k < H / 4; ++k) {
                float4 ta = ((const float4*)t1a)[k];
                float4 tb4 = ((const float4*)t1b)[k];
                PK4(fA, ta, vx, 4 * k);
                PK4(fB, tb4, vx, 4 * k);
            }
            #pragma unroll
            for (int k = 0; k < H / 4; ++k) {
                float4 ha = ((const float4*)h2s[0])[k];
                float4 hb = ((const float4*)h2s[1])[k];
                PK4(fA, ha, vh, 4 * k);
                PK4(fB, hb, vh, 4 * k);
            }
        }

        // ===== activations: 4 independent chains, then ONE drain =====
        act_store(gA, lane, half, c1A, h1s[0], t1s[tb ^ 1][0]);
        act_store(gB, lane, half, c1B, h1s[1], t1s[tb ^ 1][1]);
        act_store(fA, lane, half, c2A, h2s[0], nullptr);
        act_store(fB, lane, half, c2B, h2s[1], nullptr);
        LDS_SYNC();
        tb ^= 1;
    }

    // ---- epilogue: L2 step T-1 ----
    {
        v2f fA = bias2, fB = bias2;
        const float* t1a = t1s[tb][0];
        const float* t1b = t1s[tb][1];
        #pragma unroll
        for (int k = 0; k < H / 4; ++k) {
            float4 ta = ((const float4*)t1a)[k];
            float4 tb4 = ((const float4*)t1b)[k];
            PK4(fA, ta, vx, 4 * k);
            PK4(fB, tb4, vx, 4 * k);
        }
        #pragma unroll
        for (int k = 0; k < H / 4; ++k) {
            float4 ha = ((const float4*)h2s[0])[k];
            float4 hb = ((const float4*)h2s[1])[k];
            PK4(fA, ha, vh, 4 * k);
            PK4(fB, hb, vh, 4 * k);
        }
        act_store(fA, lane, half, c2A, h2s[0], nullptr);
        act_store(fB, lane, half, c2B, h2s[1], nullptr);
    }
    LDS_SYNC();

    // ---- head: tanh -> fc1(16, relu) -> fc2(24), both rows ----
    if (lane < H) {
        t1s[0][0][lane] = tanh_fast(h2s[0][lane]);
        t1s[0][1][lane] = tanh_fast(h2s[1][lane]);
    }
    LDS_SYNC();
    if (lane < 16) {
        float accA = b1[lane], accB = b1[lane];
        #pragma unroll
        for (int j = 0; j < H; ++j) {
            float w = W1[lane * H + j];
            accA = fmaf(t1s[0][0][j], w, accA);
            accB = fmaf(t1s[0][1][j], w, accB);
        }
        h1s[0][lane] = fmaxf(accA, 0.f);
        h1s[1][lane] = fmaxf(accB, 0.f);
    }
    LDS_SYNC();
    if (lane < H) {
        float accA = b2[lane], accB = b2[lane];
        #pragma unroll
        for (int j = 0; j < 16; ++j) {
            float w = W2[lane * 16 + j];
            accA = fmaf(h1s[0][j], w, accA);
            accB = fmaf(h1s[1][j], w, accB);
        }
        out[(size_t)rowA * H + lane] = accA;
        out[(size_t)rowB * H + lane] = accB;
    }
}

extern "C" void kernel_launch(void* const* d_in, const int* in_sizes, int n_in,
                              void* d_out, int out_size, void* d_ws, size_t ws_size,
                              hipStream_t stream)
{
    const float* x    = (const float*)d_in[0];
    const float* Wih1 = (const float*)d_in[1];
    const float* Whh1 = (const float*)d_in[2];
    const float* bih1 = (const float*)d_in[3];
    const float* bhh1 = (const float*)d_in[4];
    const float* Wih2 = (const float*)d_in[5];
    const float* Whh2 = (const float*)d_in[6];
    const float* bih2 = (const float*)d_in[7];
    const float* bhh2 = (const float*)d_in[8];
    const float* W1   = (const float*)d_in[9];
    const float* b1   = (const float*)d_in[10];
    const float* W2   = (const float*)d_in[11];
    const float* b2   = (const float*)d_in[12];
    float* out = (float*)d_out;

    const int B = in_sizes[0] / (T * P);             // 4096
    hipLaunchKernelGGL(lstm2_pipe2, dim3(B / 2), dim3(64), 0, stream,
                       x, Wih1, Whh1, bih1, bhh1, Wih2, Whh2, bih2, bhh2,
                       W1, b1, W2, b2, out);
}